// Round 9
// baseline (160.001 us; speedup 1.0000x reference)
//
#include <hip/hip_runtime.h>

#define IS 256
#define NEARV 0.1f
#define FARV 100.0f
#define NTX 16                    // 16x16 tiles of 16x16 px
#define NTILES 256
#define SEGSZ 1024                // faces per segment == threads per prep block
#define NSEG 5                    // 5 segments x 1024 = 5120 >= nf
#define CAP (SEGSZ * NSEG)        // per-tile list region (segmented, 5120)
#define CHK 32                    // entries per raster chunk (r5: CHK=16 regresses)
#define KPS (SEGSZ / CHK)         // 32 chunk slots per (tile,seg)
#define NSLOT (NTILES * NSEG * KPS)   // 40960 static slots
#define RBLOCKS 2048
#define RWAVES (RBLOCKS * 4)          // 8192 waves x 5 slots = 40960 exact
#define SCRM 12347                // odd, not div by 5 -> gcd(SCRM, 40960) = 1 (bijection)

// ---------------- kernel 1: init + prep + segmented bin (2-dispatch pipeline) ----------------
// 5 blocks x 1024 threads (block == segment). zb init folded in as grid-
// strided uint4 stores (d_out holds raw float bits, atomicMin'd; positive
// floats compare as uints). Segmented binning (r2-verified, absmax 0.0):
// block b owns slots [b*SEGSZ, (b+1)*SEGSZ) of every tile's CAP region ->
// NO global atomics, NO count zeroing (cnt2 is plain-stored, every cell
// written), NO ticket/fence/scan/items. Face transform + cull + the exact
// dyadic tile-overlap predicate are VERBATIM the verified rounds.
__launch_bounds__(SEGSZ)
__global__ void kprep(const float* __restrict__ verts, const int* __restrict__ faces,
                      float4* __restrict__ fd, int* __restrict__ cnt2,
                      unsigned short* __restrict__ list, unsigned int* __restrict__ zb,
                      int nf) {
    __shared__ int scnt[NTILES];
    const int tid = threadIdx.x;
    const int bid = blockIdx.x;          // segment id
    const int gid = bid * SEGSZ + tid;

    // zb init: 16384 uint4 = 256KB of FAR bits, coalesced, grid-strided
    {
        uint4* zb4 = (uint4*)zb;
        const uint4 farv = make_uint4(0x42C80000u, 0x42C80000u, 0x42C80000u, 0x42C80000u);
        for (int i = gid; i < (IS * IS) / 4; i += NSEG * SEGSZ) zb4[i] = farv;
    }

    if (tid < NTILES) scnt[tid] = 0;
    __syncthreads();

    const int f = gid;                   // face id (segment-contiguous)
    int kx0 = 0, kx1 = -1, ky0 = 0, ky1 = -1;   // empty range for dead faces
    float bxmin = 0.f, bymin = 0.f, bxmax = -1.f, bymax = -1.f;
    if (f < nf) {
        int i0 = faces[f * 3 + 0];
        int i1 = faces[f * 3 + 1];
        int i2 = faces[f * 3 + 2];
        // transform (v - eye; R == I exactly in fp32 for this camera)
        float z0 = verts[i0 * 3 + 2] + 2.7320508075688772f;
        float z1 = verts[i1 * 3 + 2] + 2.7320508075688772f;
        float z2 = verts[i2 * 3 + 2] + 2.7320508075688772f;
        bool front = (z0 > NEARV) && (z1 > NEARV) && (z2 > NEARV);
        float zs0 = (fabsf(z0) < 1e-5f) ? 1e-5f : z0;
        float zs1 = (fabsf(z1) < 1e-5f) ? 1e-5f : z1;
        float zs2 = (fabsf(z2) < 1e-5f) ? 1e-5f : z2;
        float d0 = zs0 * 0.57735026918962576f;  // zs * tan(30 deg)
        float d1 = zs1 * 0.57735026918962576f;
        float d2 = zs2 * 0.57735026918962576f;
        float x0 = verts[i0 * 3 + 0] / d0;
        float y0 = verts[i0 * 3 + 1] / d0;
        float x1 = verts[i1 * 3 + 0] / d1;
        float y1 = verts[i1 * 3 + 1] / d1;
        float x2 = verts[i2 * 3 + 0] / d2;
        float y2 = verts[i2 * 3 + 1] / d2;
        float area = (x1 - x0) * (y2 - y0) - (x2 - x0) * (y1 - y0);
        if (front && (fabsf(area) > 1e-8f)) {
            bxmin = fminf(x0, fminf(x1, x2));
            bxmax = fmaxf(x0, fmaxf(x1, x2));
            bymin = fminf(y0, fminf(y1, y2));
            bymax = fmaxf(y0, fmaxf(y1, y2));
            float ia = 1.0f / area;  // |area| > 1e-8 so area_s == area
            float iz0 = 1.0f / fmaxf(z0, 1e-4f);
            float iz1 = 1.0f / fmaxf(z1, 1e-4f);
            float iz2 = 1.0f / fmaxf(z2, 1e-4f);
            float4* o = fd + (size_t)f * 4;
            o[0] = make_float4(x0, y0, x1, y1);
            o[1] = make_float4(x2, y2, ia, iz0);
            o[2] = make_float4(iz1, iz2, 0.0f, 0.0f);
            // conservative k-range (+/-1), exact predicate re-tested below
            float tminx = fminf(fmaxf((bxmin * 256.0f + 225.0f) * (1.0f / 32.0f), -2.0f), 17.0f);
            float tmaxx = fminf(fmaxf((bxmax * 256.0f + 255.0f) * (1.0f / 32.0f), -2.0f), 17.0f);
            float tminy = fminf(fmaxf((bymin * 256.0f + 225.0f) * (1.0f / 32.0f), -2.0f), 17.0f);
            float tmaxy = fminf(fmaxf((bymax * 256.0f + 255.0f) * (1.0f / 32.0f), -2.0f), 17.0f);
            kx0 = max(0, (int)ceilf(tminx) - 1);
            kx1 = min(NTX - 1, (int)floorf(tmaxx) + 1);
            ky0 = max(0, (int)ceilf(tminy) - 1);
            ky1 = min(NTX - 1, (int)floorf(tmaxy) + 1);
        }
    }
    // pass A: count (exact dyadic tile-overlap predicate -> bit-identical sets)
    for (int ky = ky0; ky <= ky1; ++ky) {
        float py_lo = (float)(32 * ky - 255) * (1.0f / 256.0f);
        float py_hi = (float)(32 * ky - 225) * (1.0f / 256.0f);
        if (!(bymin <= py_hi && bymax >= py_lo)) continue;
        for (int kx = kx0; kx <= kx1; ++kx) {
            float px_lo = (float)(32 * kx - 255) * (1.0f / 256.0f);
            float px_hi = (float)(32 * kx - 225) * (1.0f / 256.0f);
            if (bxmin <= px_hi && bxmax >= px_lo) atomicAdd(&scnt[ky * NTX + kx], 1);
        }
    }
    __syncthreads();
    if (tid < NTILES) {
        cnt2[tid * NSEG + bid] = scnt[tid];  // plain store; every cell written
        scnt[tid] = 0;                       // reuse as per-segment cursor
    }
    __syncthreads();
    // pass B: scatter into this block's own segment (no inter-block contention;
    // order within a tile list is irrelevant: min is commutative)
    for (int ky = ky0; ky <= ky1; ++ky) {
        float py_lo = (float)(32 * ky - 255) * (1.0f / 256.0f);
        float py_hi = (float)(32 * ky - 225) * (1.0f / 256.0f);
        if (!(bymin <= py_hi && bymax >= py_lo)) continue;
        for (int kx = kx0; kx <= kx1; ++kx) {
            float px_lo = (float)(32 * kx - 255) * (1.0f / 256.0f);
            float px_hi = (float)(32 * kx - 225) * (1.0f / 256.0f);
            if (bxmin <= px_hi && bxmax >= px_lo) {
                int t = ky * NTX + kx;
                int slot = atomicAdd(&scnt[t], 1);               // < SEGSZ by construction
                list[(size_t)t * CAP + bid * SEGSZ + slot] = (unsigned short)f;
            }
        }
    }
}

// ---------------- kernel 2: raster (scrambled static enumeration) ----------------
// 40960 (tile,seg,chunk) slots; 8192 waves x 5 slots. r4's failure was k-
// aliasing (linear map gave every wave a constant chunk index -> 1/8 of the
// waves owned all hot chunks serially). Fix: multiplicative bijection
// s' = (s * 12347) mod 40960 (gcd = 1 -> exact cover, pseudo-random spread
// over (tile,seg,k)); expected active chunks/wave ~0.33, tail ~2. Empty
// slots cost a few SALU + one wave-uniform cnt2 load (L1-hot, 5 KB).
// Inner loop = verbatim round-3 batch-staged LDS broadcast (verified):
// lanes 0..n-1 load one entry index (coalesced ushort) + 48B face record
// (3x dwordx4, ONE vmcnt batch per chunk), stage to wave-private LDS, entry
// loop reads via same-address ds_read_b128 (broadcast, conflict-free).
// Wave-internal s_waitcnt lgkmcnt(0) orders write->read (no block barrier:
// trip counts differ). Pixel math expression-identical to verified rounds;
// min3 predicate is an exact reformulation of the three sign tests. zb
// pre-read per slot; atomicMin only when it would win (zb monotone-
// decreasing -> stale read conservatively safe).
__launch_bounds__(256)
__global__ void kraster(const float4* __restrict__ fd, const unsigned short* __restrict__ list,
                        const int* __restrict__ cnt2, unsigned int* __restrict__ zb) {
    __shared__ float4 sdata[4][CHK * 3];   // 6 KB: [wave][entry*3 + part]
    const int wslot = __builtin_amdgcn_readfirstlane(threadIdx.x >> 6);
    const int wid = blockIdx.x * 4 + wslot;
    const int lane = threadIdx.x & 63;
    const int cx = lane & 15;
    const int ry = lane >> 4;
    float4* sd = &sdata[wslot][0];

#pragma unroll 1
    for (int i = 0; i < NSLOT / RWAVES; ++i) {       // 5 slots per wave
        const int s = wid + i * RWAVES;
        const int sp = (s * SCRM) % NSLOT;           // bijective scramble
        const int tile = sp & 255;
        const int rest = sp >> 8;                    // 0..159
        const int seg = rest >> 5;                   // 0..4
        const int k = rest & 31;                     // chunk in segment
        const int c = cnt2[tile * NSEG + seg];       // wave-uniform -> s_load, L1-hot
        const int n0 = c - k * CHK;
        if (n0 <= 0) continue;
        const int n = min(CHK, n0);

        const int bx = tile & 15;
        const int by = tile >> 4;
        const int j = bx * 16 + cx;
        const float px = ((float)(2 * j + 1) - 256.0f) * (1.0f / 256.0f);
        float py[4];
        int row[4];
        unsigned int zcur[4];
#pragma unroll
        for (int r = 0; r < 4; ++r) {
            row[r] = by * 16 + ry + 4 * r;
            py[r] = ((float)(2 * row[r] + 1) - 256.0f) * (1.0f / 256.0f);
            zcur[r] = zb[row[r] * IS + j];
        }
        // ---- stage this chunk's face records into wave-private LDS ----
        const unsigned short* lp = list + (size_t)tile * CAP + seg * SEGSZ + k * CHK;
        if (lane < n) {
            const int fidx = lp[lane];                 // coalesced 2B/lane
            const float4* p = fd + (size_t)fidx * 4;   // 3 dwordx4, batched vmcnt
            float4 b0 = p[0];
            float4 b1 = p[1];
            float4 b2 = p[2];
            sd[lane * 3 + 0] = b0;
            sd[lane * 3 + 1] = b1;
            sd[lane * 3 + 2] = b2;
        }
        // wave-internal write->read ordering (no block barrier)
        asm volatile("s_waitcnt lgkmcnt(0)" ::: "memory");

        float mx[4] = {0.0f, 0.0f, 0.0f, 0.0f};

#pragma unroll 2
        for (int e = 0; e < n; ++e) {
            float4 a0 = sd[e * 3 + 0];   // uniform addr -> LDS broadcast
            float4 a1 = sd[e * 3 + 1];
            float4 a2 = sd[e * 3 + 2];
            float dx0 = a0.x - px, dx1 = a0.z - px, dx2 = a1.x - px;
#pragma unroll
            for (int r = 0; r < 4; ++r) {
                float dy0 = a0.y - py[r], dy1 = a0.w - py[r], dy2 = a1.y - py[r];
                float e0 = dx1 * dy2 - dx2 * dy1;
                float e1 = dx2 * dy0 - dx0 * dy2;
                float w0 = e0 * a1.z;
                float w1 = e1 * a1.z;
                float w2 = 1.0f - w0 - w1;
                float invz = w0 * a1.w + w1 * a2.x + w2 * a2.y;
                float invzc = fmaxf(invz, 1e-6f);
                // all(w>=0) <=> min3(w0,w1,w2)>=0 (exact; mult by positive ia
                // preserves sign). valid NEAR<zp<FAR <=> 0.01 < invzc < 10.
                float wmin = fminf(fminf(w0, w1), w2);
                bool ok = (wmin >= 0.0f) && (invzc < 10.0f) && (invzc > 0.01f);
                if (ok) mx[r] = fmaxf(mx[r], invzc);
            }
        }
#pragma unroll
        for (int r = 0; r < 4; ++r) {
            if (mx[r] > 0.0f) {
                float zp = 1.0f / mx[r];  // correctly-rounded 1/x monotone => min-exact
                unsigned int zbits = __float_as_uint(zp);
                if (zbits < zcur[r]) atomicMin(&zb[row[r] * IS + j], zbits);
            }
        }
    }
}

extern "C" void kernel_launch(void* const* d_in, const int* in_sizes, int n_in,
                              void* d_out, int out_size, void* d_ws, size_t ws_size,
                              hipStream_t stream) {
    const float* verts = (const float*)d_in[0];
    const int* faces = (const int*)d_in[1];
    unsigned int* zb = (unsigned int*)d_out;  // float bits, min'd in place

    const int nf = in_sizes[1] / 3;  // 5000 (<= CAP, < 65536: ushort indices ok)

    char* ws = (char*)d_ws;
    size_t off = 0;
    float4* fd = (float4*)(ws + off);     off += (size_t)nf * 64;              // 320 KB
    off = (off + 255) & ~(size_t)255;
    int* cnt2 = (int*)(ws + off);         off += (size_t)NTILES * NSEG * 4;    // 5 KB
    off = (off + 255) & ~(size_t)255;
    unsigned short* list = (unsigned short*)(ws + off);  // 256*5120*2 = 2.62 MB

    kprep<<<NSEG, SEGSZ, 0, stream>>>(verts, faces, fd, cnt2, list, zb, nf);
    kraster<<<RBLOCKS, 256, 0, stream>>>(fd, list, cnt2, zb);
}